// Round 4
// baseline (215.611 us; speedup 1.0000x reference)
//
#include <hip/hip_runtime.h>

#define NB 32768
#define NF 256
#define H1 16
#define H2 8
#define FG 16                    // features per block
#define RJ 8                     // rows per lane (4 float2 pairs)
#define NP (RJ / 2)              // row pairs per lane
#define ROWS_PER_BLOCK (16 * RJ) // 128 rows per block

typedef float v2f __attribute__((ext_vector_type(2)));

__device__ __forceinline__ v2f splat2(float s) { v2f v = {s, s}; return v; }

// packed fma: 1x v_pk_fma_f32 instead of 2x v_fma_f32
__device__ __forceinline__ v2f fma2(v2f a, float b, v2f c) {
    return __builtin_elementwise_fma(a, splat2(b), c);
}

// ELU on a row-pair: exp/cmp/cndmask are per-component (no packed
// transcendental on CDNA), the -1 packs.
__device__ __forceinline__ v2f elu2(v2f t) {
    v2f e;
    e.x = __expf(t.x);
    e.y = __expf(t.y);
    e = e + splat2(-1.0f);                 // v_pk_add_f32
    v2f r;
    r.x = t.x > 0.0f ? t.x : e.x;
    r.y = t.y > 0.0f ? t.y : e.y;
    return r;
}

// Init: y = bias (atomic accumulation target), w_out = softplus(theta).
__global__ __launch_bounds__(256)
void nul_init(const float* __restrict__ theta, const float* __restrict__ bias,
              float* __restrict__ y_out, float* __restrict__ w_out) {
    const int t = blockIdx.x * 256 + threadIdx.x;     // grid covers NB
    if (t < NB) y_out[t] = bias[0];
    if (t < NF) w_out[t] = __logf(1.0f + __expf(theta[t]));
}

// Main: lane=(row_lane, feature_lane); 16 features/block, params in LDS.
// RJ=8 rows per lane processed as 4 float2 row-pairs -> v_pk_fma_f32
// halves issue cycles of the whole FMA stream (R3 was scalar-issue bound:
// VALU busy 54us of 78us).
__global__ __launch_bounds__(256)
void nul_main(const float* __restrict__ x,
              const float* __restrict__ W1, const float* __restrict__ b1,
              const float* __restrict__ W2, const float* __restrict__ b2,
              const float* __restrict__ W3, const float* __restrict__ b3,
              const float* __restrict__ theta,
              float* __restrict__ y_out, float* __restrict__ z_out) {
    __shared__ __align__(16) float sW1[FG][17];
    __shared__ __align__(16) float sB1[FG][17];
    __shared__ __align__(16) float sW2[FG][132];   // float4-aligned rows
    __shared__ __align__(16) float sB2[FG][12];
    __shared__ __align__(16) float sW3[FG][12];
    __shared__ float sB3[FG];
    __shared__ float sWv[FG];

    const int tid  = threadIdx.x;
    const int f0   = blockIdx.y * FG;
    const int row0 = blockIdx.x * ROWS_PER_BLOCK;

    // ---- cooperative param staging (once per block) ----
    {
        const int f = tid >> 4, h = tid & 15;          // 256 threads = 16f x 16h
        sW1[f][h] = W1[(f0 + f) * H1 + h];
        sB1[f][h] = b1[(f0 + f) * H1 + h];
    }
    {
        const int e = tid * 8;                          // 2048 floats of W2
        const int ff = e >> 7, c = e & 127;
        const float4* p = reinterpret_cast<const float4*>(W2 + (f0 + ff) * (H1 * H2) + c);
        float4 v0 = p[0], v1 = p[1];
        float* d = &sW2[ff][c];
        d[0] = v0.x; d[1] = v0.y; d[2] = v0.z; d[3] = v0.w;
        d[4] = v1.x; d[5] = v1.y; d[6] = v1.z; d[7] = v1.w;
    }
    if (tid < FG * H2) {
        const int f = tid >> 3, k = tid & 7;
        sB2[f][k] = b2[(f0 + f) * H2 + k];
        sW3[f][k] = W3[(f0 + f) * H2 + k];
    }
    if (tid < FG) {
        sB3[tid] = b3[f0 + tid];
        sWv[tid] = __logf(1.0f + __expf(theta[f0 + tid]));
    }
    __syncthreads();

    const int fl = tid & 15;        // feature lane
    const int rl = tid >> 4;        // row lane (0..15 across block)
    const int f  = f0 + fl;

    // x loads: rows row0 + rl + 16*j, pair j=(2p, 2p+1)
    v2f xv[NP];
    #pragma unroll
    for (int p = 0; p < NP; ++p) {
        xv[p].x = x[(row0 + rl + 16 * (2 * p + 0)) * NF + f];
        xv[p].y = x[(row0 + rl + 16 * (2 * p + 1)) * NF + f];
    }

    v2f acc[NP][H2];
    {
        const float4 ba = *reinterpret_cast<const float4*>(&sB2[fl][0]);
        const float4 bb = *reinterpret_cast<const float4*>(&sB2[fl][4]);
        #pragma unroll
        for (int p = 0; p < NP; ++p) {
            acc[p][0] = splat2(ba.x); acc[p][1] = splat2(ba.y);
            acc[p][2] = splat2(ba.z); acc[p][3] = splat2(ba.w);
            acc[p][4] = splat2(bb.x); acc[p][5] = splat2(bb.y);
            acc[p][6] = splat2(bb.z); acc[p][7] = splat2(bb.w);
        }
    }

    #pragma unroll
    for (int hq = 0; hq < H1 / 4; ++hq) {
        // vector LDS reads for w1/b1 (4 h-steps at a time)
        const float4 w1q = *reinterpret_cast<const float4*>(&sW1[fl][hq * 4]);
        const float4 b1q = *reinterpret_cast<const float4*>(&sB1[fl][hq * 4]);
        const float w1a[4] = {w1q.x, w1q.y, w1q.z, w1q.w};
        const float b1a[4] = {b1q.x, b1q.y, b1q.z, b1q.w};
        #pragma unroll
        for (int hh = 0; hh < 4; ++hh) {
            const int h = hq * 4 + hh;
            const float4 wa = *reinterpret_cast<const float4*>(&sW2[fl][h * 8]);
            const float4 wb = *reinterpret_cast<const float4*>(&sW2[fl][h * 8 + 4]);
            #pragma unroll
            for (int p = 0; p < NP; ++p) {
                const v2f h1 = elu2(fma2(xv[p], w1a[hh], splat2(b1a[hh])));
                acc[p][0] = fma2(h1, wa.x, acc[p][0]);
                acc[p][1] = fma2(h1, wa.y, acc[p][1]);
                acc[p][2] = fma2(h1, wa.z, acc[p][2]);
                acc[p][3] = fma2(h1, wa.w, acc[p][3]);
                acc[p][4] = fma2(h1, wb.x, acc[p][4]);
                acc[p][5] = fma2(h1, wb.y, acc[p][5]);
                acc[p][6] = fma2(h1, wb.z, acc[p][6]);
                acc[p][7] = fma2(h1, wb.w, acc[p][7]);
            }
        }
    }

    const float4 w3a = *reinterpret_cast<const float4*>(&sW3[fl][0]);
    const float4 w3b = *reinterpret_cast<const float4*>(&sW3[fl][4]);
    const float  b3v = sB3[fl];
    const float  wv  = sWv[fl];

    #pragma unroll
    for (int p = 0; p < NP; ++p) {
        v2f z = splat2(b3v);
        z = fma2(elu2(acc[p][0]), w3a.x, z);
        z = fma2(elu2(acc[p][1]), w3a.y, z);
        z = fma2(elu2(acc[p][2]), w3a.z, z);
        z = fma2(elu2(acc[p][3]), w3a.w, z);
        z = fma2(elu2(acc[p][4]), w3b.x, z);
        z = fma2(elu2(acc[p][5]), w3b.y, z);
        z = fma2(elu2(acc[p][6]), w3b.z, z);
        z = fma2(elu2(acc[p][7]), w3b.w, z);

        const int rowA = row0 + rl + 16 * (2 * p + 0);
        const int rowB = row0 + rl + 16 * (2 * p + 1);
        z_out[rowA * NF + f] = z.x;              // full-line coalesced per wave
        z_out[rowB * NF + f] = z.y;

        v2f q = z * splat2(wv);                  // y partials over 16 features
        q.x += __shfl_xor(q.x, 1, 16);
        q.y += __shfl_xor(q.y, 1, 16);
        q.x += __shfl_xor(q.x, 2, 16);
        q.y += __shfl_xor(q.y, 2, 16);
        q.x += __shfl_xor(q.x, 4, 16);
        q.y += __shfl_xor(q.y, 4, 16);
        q.x += __shfl_xor(q.x, 8, 16);
        q.y += __shfl_xor(q.y, 8, 16);
        if (fl == 0) {
            unsafeAtomicAdd(&y_out[rowA], q.x);
            unsafeAtomicAdd(&y_out[rowB], q.y);
        }
    }
}

extern "C" void kernel_launch(void* const* d_in, const int* in_sizes, int n_in,
                              void* d_out, int out_size, void* d_ws, size_t ws_size,
                              hipStream_t stream) {
    const float* x     = (const float*)d_in[0];
    const float* W1    = (const float*)d_in[1];
    const float* b1    = (const float*)d_in[2];
    const float* W2    = (const float*)d_in[3];
    const float* b2    = (const float*)d_in[4];
    const float* W3    = (const float*)d_in[5];
    const float* b3    = (const float*)d_in[6];
    const float* theta = (const float*)d_in[7];
    const float* bias  = (const float*)d_in[8];

    float* y_out = (float*)d_out;                  // [32768]
    float* w_out = y_out + NB;                     // [256]
    float* z_out = w_out + NF;                     // [32768*256]

    nul_init<<<NB / 256, 256, 0, stream>>>(theta, bias, y_out, w_out);

    dim3 grid(NB / ROWS_PER_BLOCK, NF / FG);       // (256, 16)
    nul_main<<<grid, 256, 0, stream>>>(
        x, W1, b1, W2, b2, W3, b3, theta, y_out, z_out);
}

// Round 5
// 161.403 us; speedup vs baseline: 1.3359x; 1.3359x over previous
//
#include <hip/hip_runtime.h>

#define NB 32768
#define NF 256
#define H1 16
#define H2 8
#define FG 16                    // features per block
#define RJ 4                     // rows per lane (R5: 8->4 to halve acc VGPRs)
#define ROWS_PER_BLOCK (16 * RJ) // 64 rows per block

__device__ __forceinline__ float elu_f(float v) {
    return v > 0.0f ? v : (__expf(v) - 1.0f);
}

// Init: y = bias (atomic accumulation target), w_out = softplus(theta).
__global__ __launch_bounds__(256)
void nul_init(const float* __restrict__ theta, const float* __restrict__ bias,
              float* __restrict__ y_out, float* __restrict__ w_out) {
    const int t = blockIdx.x * 256 + threadIdx.x;     // grid covers NB
    if (t < NB) y_out[t] = bias[0];
    if (t < NF) w_out[t] = __logf(1.0f + __expf(theta[t]));
}

// Main: lane=(row_lane, feature_lane); 16 features/block, params in LDS.
// RJ=4 rows/lane: acc = 32 VGPRs -> target 5-6 waves/SIMD (R3: VGPR=116
// capped at 4 waves, 24us of 78us was stall; R4's float2 packing regressed
// to VGPR=200 / 140us -- scalar issue, low pressure is the winning mix).
__global__ __launch_bounds__(256)
void nul_main(const float* __restrict__ x,
              const float* __restrict__ W1, const float* __restrict__ b1,
              const float* __restrict__ W2, const float* __restrict__ b2,
              const float* __restrict__ W3, const float* __restrict__ b3,
              const float* __restrict__ theta,
              float* __restrict__ y_out, float* __restrict__ z_out) {
    __shared__ __align__(16) float sW1[FG][17];
    __shared__ __align__(16) float sB1[FG][17];
    __shared__ __align__(16) float sW2[FG][132];   // float4-aligned rows
    __shared__ __align__(16) float sB2[FG][12];
    __shared__ __align__(16) float sW3[FG][12];
    __shared__ float sB3[FG];
    __shared__ float sWv[FG];

    const int tid  = threadIdx.x;
    const int f0   = blockIdx.y * FG;
    const int row0 = blockIdx.x * ROWS_PER_BLOCK;

    // ---- cooperative param staging (once per block) ----
    {
        const int f = tid >> 4, h = tid & 15;          // 256 threads = 16f x 16h
        sW1[f][h] = W1[(f0 + f) * H1 + h];
        sB1[f][h] = b1[(f0 + f) * H1 + h];
    }
    {
        const int e = tid * 8;                          // 2048 floats of W2
        const int ff = e >> 7, c = e & 127;
        const float4* p = reinterpret_cast<const float4*>(W2 + (f0 + ff) * (H1 * H2) + c);
        float4 v0 = p[0], v1 = p[1];
        float* d = &sW2[ff][c];
        d[0] = v0.x; d[1] = v0.y; d[2] = v0.z; d[3] = v0.w;
        d[4] = v1.x; d[5] = v1.y; d[6] = v1.z; d[7] = v1.w;
    }
    if (tid < FG * H2) {
        const int f = tid >> 3, k = tid & 7;
        sB2[f][k] = b2[(f0 + f) * H2 + k];
        sW3[f][k] = W3[(f0 + f) * H2 + k];
    }
    if (tid < FG) {
        sB3[tid] = b3[f0 + tid];
        sWv[tid] = __logf(1.0f + __expf(theta[f0 + tid]));
    }
    __syncthreads();

    const int fl = tid & 15;        // feature lane
    const int rl = tid >> 4;        // row lane (0..15 across block)
    const int f  = f0 + fl;

    // x loads: per wave, 4 row-groups x 16 features = fully-used 64B lines
    float xv[RJ];
    #pragma unroll
    for (int j = 0; j < RJ; ++j)
        xv[j] = x[(row0 + rl + 16 * j) * NF + f];

    float acc[RJ][H2];
    {
        const float4 ba = *reinterpret_cast<const float4*>(&sB2[fl][0]);
        const float4 bb = *reinterpret_cast<const float4*>(&sB2[fl][4]);
        #pragma unroll
        for (int j = 0; j < RJ; ++j) {
            acc[j][0] = ba.x; acc[j][1] = ba.y; acc[j][2] = ba.z; acc[j][3] = ba.w;
            acc[j][4] = bb.x; acc[j][5] = bb.y; acc[j][6] = bb.z; acc[j][7] = bb.w;
        }
    }

    #pragma unroll
    for (int hq = 0; hq < H1 / 4; ++hq) {
        // vector LDS reads for w1/b1 (4 h-steps at a time)
        const float4 w1q = *reinterpret_cast<const float4*>(&sW1[fl][hq * 4]);
        const float4 b1q = *reinterpret_cast<const float4*>(&sB1[fl][hq * 4]);
        const float w1a[4] = {w1q.x, w1q.y, w1q.z, w1q.w};
        const float b1a[4] = {b1q.x, b1q.y, b1q.z, b1q.w};
        #pragma unroll
        for (int hh = 0; hh < 4; ++hh) {
            const int h = hq * 4 + hh;
            const float4 wa = *reinterpret_cast<const float4*>(&sW2[fl][h * 8]);
            const float4 wb = *reinterpret_cast<const float4*>(&sW2[fl][h * 8 + 4]);
            #pragma unroll
            for (int j = 0; j < RJ; ++j) {
                const float h1 = elu_f(fmaf(xv[j], w1a[hh], b1a[hh]));
                acc[j][0] = fmaf(h1, wa.x, acc[j][0]);
                acc[j][1] = fmaf(h1, wa.y, acc[j][1]);
                acc[j][2] = fmaf(h1, wa.z, acc[j][2]);
                acc[j][3] = fmaf(h1, wa.w, acc[j][3]);
                acc[j][4] = fmaf(h1, wb.x, acc[j][4]);
                acc[j][5] = fmaf(h1, wb.y, acc[j][5]);
                acc[j][6] = fmaf(h1, wb.z, acc[j][6]);
                acc[j][7] = fmaf(h1, wb.w, acc[j][7]);
            }
        }
    }

    const float4 w3a = *reinterpret_cast<const float4*>(&sW3[fl][0]);
    const float4 w3b = *reinterpret_cast<const float4*>(&sW3[fl][4]);
    const float  b3v = sB3[fl];
    const float  wv  = sWv[fl];

    #pragma unroll
    for (int j = 0; j < RJ; ++j) {
        float z = b3v;
        z = fmaf(elu_f(acc[j][0]), w3a.x, z);
        z = fmaf(elu_f(acc[j][1]), w3a.y, z);
        z = fmaf(elu_f(acc[j][2]), w3a.z, z);
        z = fmaf(elu_f(acc[j][3]), w3a.w, z);
        z = fmaf(elu_f(acc[j][4]), w3b.x, z);
        z = fmaf(elu_f(acc[j][5]), w3b.y, z);
        z = fmaf(elu_f(acc[j][6]), w3b.z, z);
        z = fmaf(elu_f(acc[j][7]), w3b.w, z);

        const int row = row0 + rl + 16 * j;
        z_out[row * NF + f] = z;                 // full-line coalesced per wave

        float p = wv * z;                        // y partial over 16 features
        p += __shfl_xor(p, 1, 16);
        p += __shfl_xor(p, 2, 16);
        p += __shfl_xor(p, 4, 16);
        p += __shfl_xor(p, 8, 16);
        if (fl == 0) unsafeAtomicAdd(&y_out[row], p);
    }
}

extern "C" void kernel_launch(void* const* d_in, const int* in_sizes, int n_in,
                              void* d_out, int out_size, void* d_ws, size_t ws_size,
                              hipStream_t stream) {
    const float* x     = (const float*)d_in[0];
    const float* W1    = (const float*)d_in[1];
    const float* b1    = (const float*)d_in[2];
    const float* W2    = (const float*)d_in[3];
    const float* b2    = (const float*)d_in[4];
    const float* W3    = (const float*)d_in[5];
    const float* b3    = (const float*)d_in[6];
    const float* theta = (const float*)d_in[7];
    const float* bias  = (const float*)d_in[8];

    float* y_out = (float*)d_out;                  // [32768]
    float* w_out = y_out + NB;                     // [256]
    float* z_out = w_out + NF;                     // [32768*256]

    nul_init<<<NB / 256, 256, 0, stream>>>(theta, bias, y_out, w_out);

    dim3 grid(NB / ROWS_PER_BLOCK, NF / FG);       // (512, 16)
    nul_main<<<grid, 256, 0, stream>>>(
        x, W1, b1, W2, b2, W3, b3, theta, y_out, z_out);
}

// Round 6
// 149.442 us; speedup vs baseline: 1.4428x; 1.0800x over previous
//
#include <hip/hip_runtime.h>

#define NB 32768
#define NF 256
#define H1 16
#define H2 8
#define FG 16                                 // features per block
#define RJ 8                                  // rows per lane per chunk
#define RT 4                                  // chunks per block (amortize startup)
#define ROWS_PER_CHUNK (16 * RJ)              // 128
#define ROWS_PER_BLOCK (ROWS_PER_CHUNK * RT)  // 512

__device__ __forceinline__ float elu_f(float v) {
    return v > 0.0f ? v : (__expf(v) - 1.0f);
}

// one-op cross-lane add via ds_swizzle (vs ~4 ops for HIP __shfl_xor)
template <int PAT>
__device__ __forceinline__ float swz_add(float p) {
    return p + __int_as_float(__builtin_amdgcn_ds_swizzle(__float_as_int(p), PAT));
}

// Init: y = bias (atomic accumulation target), w_out = softplus(theta).
__global__ __launch_bounds__(256)
void nul_init(const float* __restrict__ theta, const float* __restrict__ bias,
              float* __restrict__ y_out, float* __restrict__ w_out) {
    const int t = blockIdx.x * 256 + threadIdx.x;
    if (t < NB) y_out[t] = bias[0];
    if (t < NF) w_out[t] = __logf(1.0f + __expf(theta[t]));
}

// R6: R3 structure (lane=(row,feature), params in LDS, RJ=8) + RT=4 chunk
// loop per block. Params staged ONCE per 512 rows; next chunk's 8 x-loads
// issued before current chunk's ~4.4k-cy compute so the ~900cy HBM latency
// hides. R3/R5 evidence: per-block startup (cold x loads + staging barrier)
// was the ~24-30us stall share; issue side is ~54us and untouched here.
__global__ __launch_bounds__(256)
void nul_main(const float* __restrict__ x,
              const float* __restrict__ W1, const float* __restrict__ b1,
              const float* __restrict__ W2, const float* __restrict__ b2,
              const float* __restrict__ W3, const float* __restrict__ b3,
              const float* __restrict__ theta,
              float* __restrict__ y_out, float* __restrict__ z_out) {
    __shared__ __align__(16) float sW1[FG][17];
    __shared__ __align__(16) float sB1[FG][17];
    __shared__ __align__(16) float sW2[FG][132];   // float4-aligned rows
    __shared__ __align__(16) float sB2[FG][12];
    __shared__ __align__(16) float sW3[FG][12];
    __shared__ float sB3[FG];
    __shared__ float sWv[FG];

    const int tid  = threadIdx.x;
    const int f0   = blockIdx.y * FG;
    const int row0 = blockIdx.x * ROWS_PER_BLOCK;

    // ---- cooperative param staging (ONCE per block, 512 rows) ----
    {
        const int f = tid >> 4, h = tid & 15;
        sW1[f][h] = W1[(f0 + f) * H1 + h];
        sB1[f][h] = b1[(f0 + f) * H1 + h];
    }
    {
        const int e = tid * 8;                          // 2048 floats of W2
        const int ff = e >> 7, c = e & 127;
        const float4* p = reinterpret_cast<const float4*>(W2 + (f0 + ff) * (H1 * H2) + c);
        float4 v0 = p[0], v1 = p[1];
        float* d = &sW2[ff][c];
        d[0] = v0.x; d[1] = v0.y; d[2] = v0.z; d[3] = v0.w;
        d[4] = v1.x; d[5] = v1.y; d[6] = v1.z; d[7] = v1.w;
    }
    if (tid < FG * H2) {
        const int f = tid >> 3, k = tid & 7;
        sB2[f][k] = b2[(f0 + f) * H2 + k];
        sW3[f][k] = W3[(f0 + f) * H2 + k];
    }
    if (tid < FG) {
        sB3[tid] = b3[f0 + tid];
        sWv[tid] = __logf(1.0f + __expf(theta[f0 + tid]));
    }
    __syncthreads();

    const int fl = tid & 15;        // feature lane
    const int rl = tid >> 4;        // row lane (0..15 across block)
    const int f  = f0 + fl;

    // per-lane hoists (invariant across chunks)
    const float4 ba  = *reinterpret_cast<const float4*>(&sB2[fl][0]);
    const float4 bb  = *reinterpret_cast<const float4*>(&sB2[fl][4]);
    const float4 w3a = *reinterpret_cast<const float4*>(&sW3[fl][0]);
    const float4 w3b = *reinterpret_cast<const float4*>(&sW3[fl][4]);
    const float  b3v = sB3[fl];
    const float  wv  = sWv[fl];
    const float* xcol = x + f;

    // chunk-0 x loads (the only cold stall of the block's life)
    float xv[RJ];
    #pragma unroll
    for (int j = 0; j < RJ; ++j)
        xv[j] = xcol[(row0 + rl + 16 * j) * NF];

    #pragma unroll 1
    for (int c = 0; c < RT; ++c) {
        const int rbase = row0 + c * ROWS_PER_CHUNK;

        // prefetch next chunk's x BEFORE compute: ~900cy latency hides
        // under the h-loop's ~4.4k cy
        float xn[RJ];
        if (c + 1 < RT) {
            #pragma unroll
            for (int j = 0; j < RJ; ++j)
                xn[j] = xcol[(rbase + ROWS_PER_CHUNK + rl + 16 * j) * NF];
        }

        float acc[RJ][H2];
        #pragma unroll
        for (int j = 0; j < RJ; ++j) {
            acc[j][0] = ba.x; acc[j][1] = ba.y; acc[j][2] = ba.z; acc[j][3] = ba.w;
            acc[j][4] = bb.x; acc[j][5] = bb.y; acc[j][6] = bb.z; acc[j][7] = bb.w;
        }

        #pragma unroll
        for (int hq = 0; hq < H1 / 4; ++hq) {
            const float4 w1q = *reinterpret_cast<const float4*>(&sW1[fl][hq * 4]);
            const float4 b1q = *reinterpret_cast<const float4*>(&sB1[fl][hq * 4]);
            const float w1a[4] = {w1q.x, w1q.y, w1q.z, w1q.w};
            const float b1a[4] = {b1q.x, b1q.y, b1q.z, b1q.w};
            #pragma unroll
            for (int hh = 0; hh < 4; ++hh) {
                const int h = hq * 4 + hh;
                const float4 wa = *reinterpret_cast<const float4*>(&sW2[fl][h * 8]);
                const float4 wb = *reinterpret_cast<const float4*>(&sW2[fl][h * 8 + 4]);
                #pragma unroll
                for (int j = 0; j < RJ; ++j) {
                    const float h1 = elu_f(fmaf(xv[j], w1a[hh], b1a[hh]));
                    acc[j][0] = fmaf(h1, wa.x, acc[j][0]);
                    acc[j][1] = fmaf(h1, wa.y, acc[j][1]);
                    acc[j][2] = fmaf(h1, wa.z, acc[j][2]);
                    acc[j][3] = fmaf(h1, wa.w, acc[j][3]);
                    acc[j][4] = fmaf(h1, wb.x, acc[j][4]);
                    acc[j][5] = fmaf(h1, wb.y, acc[j][5]);
                    acc[j][6] = fmaf(h1, wb.z, acc[j][6]);
                    acc[j][7] = fmaf(h1, wb.w, acc[j][7]);
                }
            }
        }

        #pragma unroll
        for (int j = 0; j < RJ; ++j) {
            float z = b3v;
            z = fmaf(elu_f(acc[j][0]), w3a.x, z);
            z = fmaf(elu_f(acc[j][1]), w3a.y, z);
            z = fmaf(elu_f(acc[j][2]), w3a.z, z);
            z = fmaf(elu_f(acc[j][3]), w3a.w, z);
            z = fmaf(elu_f(acc[j][4]), w3b.x, z);
            z = fmaf(elu_f(acc[j][5]), w3b.y, z);
            z = fmaf(elu_f(acc[j][6]), w3b.z, z);
            z = fmaf(elu_f(acc[j][7]), w3b.w, z);

            const int row = rbase + rl + 16 * j;
            z_out[row * NF + f] = z;             // full-line coalesced per wave

            // y partial: allreduce over the 16 feature lanes (ds_swizzle xor)
            float p = wv * z;
            p = swz_add<0x041F>(p);              // xor 1
            p = swz_add<0x081F>(p);              // xor 2
            p = swz_add<0x101F>(p);              // xor 4
            p = swz_add<0x201F>(p);              // xor 8
            if (fl == 0) unsafeAtomicAdd(&y_out[row], p);
        }

        if (c + 1 < RT) {
            #pragma unroll
            for (int j = 0; j < RJ; ++j) xv[j] = xn[j];
        }
    }
}

extern "C" void kernel_launch(void* const* d_in, const int* in_sizes, int n_in,
                              void* d_out, int out_size, void* d_ws, size_t ws_size,
                              hipStream_t stream) {
    const float* x     = (const float*)d_in[0];
    const float* W1    = (const float*)d_in[1];
    const float* b1    = (const float*)d_in[2];
    const float* W2    = (const float*)d_in[3];
    const float* b2    = (const float*)d_in[4];
    const float* W3    = (const float*)d_in[5];
    const float* b3    = (const float*)d_in[6];
    const float* theta = (const float*)d_in[7];
    const float* bias  = (const float*)d_in[8];

    float* y_out = (float*)d_out;                  // [32768]
    float* w_out = y_out + NB;                     // [256]
    float* z_out = w_out + NF;                     // [32768*256]

    nul_init<<<NB / 256, 256, 0, stream>>>(theta, bias, y_out, w_out);

    dim3 grid(NB / ROWS_PER_BLOCK, NF / FG);       // (64, 16) = 1024 blocks = 4/CU
    nul_main<<<grid, 256, 0, stream>>>(
        x, W1, b1, W2, b2, W3, b3, theta, y_out, z_out);
}